// Round 5
// baseline (834.298 us; speedup 1.0000x reference)
//
#include <hip/hip_runtime.h>
#include <cstdint>
#include <cstddef>

typedef unsigned long long u64;
typedef unsigned int u32;
typedef __attribute__((ext_vector_type(8))) short short8;
typedef __attribute__((ext_vector_type(4))) float f32x4;

#define NBOX 100800
#define CAND_CAP 4096
#define BPAD 36   // hood pixel stride (shorts)

// ---------------- workspace layout (bytes) ----------------
#define OFF_WTH0 ((size_t)0)
#define OFF_WTH1 ((size_t)18874368)
#define OFF_WTH2 ((size_t)23592960)
#define OFF_WTL0 ((size_t)24772608)
#define OFF_WTL1 ((size_t)43646976)
#define OFF_WTL2 ((size_t)48365568)
#define OFF_Y0   ((size_t)49545216)
#define OFF_Y1   ((size_t)56098816)
#define OFF_Y2   ((size_t)69206016)
#define OFF_KEYS ((size_t)95420416)
#define OFF_HIST ((size_t)96226816)   // 262144
#define OFF_META ((size_t)96488960)   // 64
#define OFF_LOG  ((size_t)96489024)   // 100800*4 = 403200 (zeroed with hist+meta)
#define OFF_CAND ((size_t)96892224)   // 32768
#define OFF_SEL  ((size_t)96924992)   // 1024
#define OFF_XTH0 ((size_t)96926016)
#define OFF_XTH1 ((size_t)100202816)
#define OFF_XTH2 ((size_t)106756416)
#define OFF_XTL0 ((size_t)119863616)
#define OFF_XTL1 ((size_t)123140416)
#define OFF_XTL2 ((size_t)129694016)
#define NEED_FULL ((size_t)142801216)
#define MEMSET_LEN ((size_t)(262144 + 64 + 403200))
#define Y01_LEN   ((size_t)(6553600 + 13107200))   // y0 + y1 zeroed for K-split atomics

// ---------------- bf16 helpers (RNE, finite inputs) ----------------
__device__ __forceinline__ short f2bf(float f) {
    u32 u = __float_as_uint(f);
    u = (u + 0x7fffu + ((u >> 16) & 1u)) >> 16;
    return (short)u;
}
__device__ __forceinline__ float bf2f(short h) {
    return __uint_as_float(((u32)(unsigned short)h) << 16);
}

// ---- weight prep: (co,ci,3,3) f32 -> fragment-ordered bf16 hi/lo ----
// Layout: [my(co/128)][ch(ci/32)][tap(9)][m(128)][ci(32)]
// Per (wm,mt) MFMA A-fragment = one contiguous, aligned 1KB block:
// lane (l15,quad) reads shorts [(m)*32 + quad*8 .. +8) -> perfectly coalesced.
__global__ __launch_bounds__(256) void prep_w_kernel(
    const float* __restrict__ w, short* __restrict__ wh, short* __restrict__ wl, int C)
{
    __shared__ float ws_[2304];
    int chunks256 = C >> 8;
    int co = blockIdx.x / chunks256;
    int ci0 = (blockIdx.x % chunks256) << 8;
    size_t base = ((size_t)co * C + ci0) * 9;
    for (int idx = threadIdx.x; idx < 2304; idx += 256) ws_[idx] = w[base + idx];
    __syncthreads();
    int my = co >> 7, m = co & 127;
    int chunksW = C >> 5;
    for (int idx = threadIdx.x; idx < 2304; idx += 256) {
        int tap = idx >> 8, ci = idx & 255;
        float v = ws_[ci * 9 + tap];
        short h = f2bf(v);
        short l = f2bf(v - bf2f(h));
        int gci = ci0 + ci;
        int ch = gci >> 5, ciw = gci & 31;
        size_t o = ((((size_t)my * chunksW + ch) * 9 + tap) * 128 + m) * 32 + ciw;
        wh[o] = h; wl[o] = l;
    }
}

// ---------------- input prep: [C][HW] f32 -> [pix][C] bf16 hi/lo (transpose) --
struct PrepX { const float* x; short* xh; short* xl; int C, HW, bbase, ptiles; };

__global__ __launch_bounds__(256) void prep_x_kernel(PrepX p0, PrepX p1, PrepX p2)
{
    PrepX p = (blockIdx.x >= (u32)p2.bbase) ? p2 :
              (blockIdx.x >= (u32)p1.bbase) ? p1 : p0;
    int local = blockIdx.x - p.bbase;
    int pt = local % p.ptiles, ct = local / p.ptiles;
    __shared__ short th[32][34];
    __shared__ short tl[32][34];
    for (int idx = threadIdx.x; idx < 1024; idx += 256) {
        int ci = idx >> 5, px = idx & 31;
        float v = p.x[(size_t)(ct * 32 + ci) * p.HW + pt * 32 + px];
        short h = f2bf(v);
        th[ci][px] = h;
        tl[ci][px] = f2bf(v - bf2f(h));
    }
    __syncthreads();
    for (int idx = threadIdx.x; idx < 1024; idx += 256) {
        int px = idx >> 5, ci = idx & 31;
        size_t o = (size_t)(pt * 32 + px) * p.C + ct * 32 + ci;
        p.xh[o] = th[ci][px];
        p.xl[o] = tl[ci][px];
    }
}

// ------- fused 3-head 3x3 conv, bf16 MFMA hi/lo 3-pass, tap-reuse hood -------
// R9: R8 barrier-free structure + register diet for 3 blocks/CU:
//  - A-hi double-set prefetch (one tap ahead, under MFMAs)   [32 VGPR]
//  - A-lo SINGLE-set, loaded at tap start; only consumed by pass 3, so
//    ~200cy of pass-1/2 MFMAs cover its L2 latency             [16 VGPR]
//  - launch_bounds(256,3): allocator targets <=170/wave -> 12 waves/CU
//  - MFMA passes reordered (hh all, hl all, lh all): 16 independent MFMAs
//    between successive writes to the same acc - scheduler-proof chains.
// K-split retained: every block does exactly 8 chunks; head0 4-way, head1
// 2-way over the reduction (partial y via atomicAdd, y pre-zeroed).
struct ConvHead {
    const float* x; const short* xh; const short* xl;
    const short* wh; const short* wl; const float* bias;
    const float* w1; float* y;
    int C, H, W, sx, nco_mask, nco_shift, kmask, kshift, chunks, bbase, lbase;
};

__global__ __launch_bounds__(256, 3) void conv3x3_mfma(
    ConvHead h0, ConvHead h1, ConvHead h2, float* __restrict__ logits, int use_xt)
{
    ConvHead h = (blockIdx.x >= (u32)h2.bbase) ? h2 :
                 (blockIdx.x >= (u32)h1.bbase) ? h1 : h0;
    const int local = blockIdx.x - h.bbase;
    const int my = local & h.nco_mask;
    const int rest = local >> h.nco_shift;
    const int kb = rest & h.kmask;
    const int sp = rest >> h.kshift;
    const int ty = sp / h.sx;
    const int tx = sp - ty * h.sx;
    const int py0 = ty * 8, px0 = tx * 16;
    const int co0 = my * 128;
    const int C = h.C, H = h.H, W = h.W, HW = H * W;

    const int tid = threadIdx.x;
    const int lane = tid & 63;
    const int wave = tid >> 6;
    const int quad = lane >> 4;
    const int l15 = lane & 15;
    const int wm = wave >> 1, wn = wave & 1;

    __shared__ short Bh_hi[180 * BPAD];   // 10 x 18 pixel hood x 32 ch
    __shared__ short Bh_lo[180 * BPAD];
    __shared__ float wobj[3][128];

    f32x4 acc[4][4];
    #pragma unroll
    for (int i = 0; i < 4; i++)
        #pragma unroll
        for (int j = 0; j < 4; j++) acc[i][j] = (f32x4){0.f, 0.f, 0.f, 0.f};

    const int chunksW = C >> 5;
    // per-lane base into fragment-ordered weights: frag (g, mt) at
    // lane_ptr + g*4096 + mt*512
    const size_t mybase = (size_t)my * chunksW * 9 * 4096;
    const int lane_off = wm * 2048 + l15 * 32 + quad * 8;
    const short* __restrict__ wh_lane = h.wh + mybase + lane_off;
    const short* __restrict__ wl_lane = h.wl + mybase + lane_off;
    const int ch0 = kb * h.chunks;

    // A-hi prefetch double-set (by tap parity); A-lo single-set per tap
    short8 pah[2][4], pal[4];

    // prologue: load A-hi frags for global tap 0
    {
        const size_t goff = (size_t)(ch0 * 9) * 4096;
        #pragma unroll
        for (int mt = 0; mt < 4; mt++)
            pah[0][mt] = *(const short8*)(wh_lane + goff + mt * 512);
    }

    for (int c = 0; c < h.chunks; ++c) {
        const int ch = ch0 + c;
        const int ci0 = ch << 5;
        __syncthreads();   // prev chunk B reads fully consumed
        // ---- stage hood: 180 pixels x 32 channels, hi/lo, zero-padded ----
        for (int idx = tid; idx < 360; idx += 256) {
            int hp = idx >> 1, half = idx & 1;
            int hy = hp / 18, hx = hp - hy * 18;
            int gy = py0 - 1 + hy, gx = px0 - 1 + hx;
            short8 vh0 = {0,0,0,0,0,0,0,0}, vh1 = {0,0,0,0,0,0,0,0};
            short8 vl0 = {0,0,0,0,0,0,0,0}, vl1 = {0,0,0,0,0,0,0,0};
            if (gy >= 0 && gy < H && gx >= 0 && gx < W) {
                if (use_xt) {
                    size_t ro = (size_t)(gy * W + gx) * C + ci0 + half * 16;
                    const short* ph = h.xh + ro;
                    const short* pl = h.xl + ro;
                    vh0 = *(const short8*)ph; vh1 = *(const short8*)(ph + 8);
                    vl0 = *(const short8*)pl; vl1 = *(const short8*)(pl + 8);
                } else {
                    const float* xp = h.x + (size_t)(ci0 + half * 16) * HW + gy * W + gx;
                    #pragma unroll
                    for (int k = 0; k < 8; k++) {
                        float v = xp[(size_t)k * HW];
                        short hh = f2bf(v); vh0[k] = hh; vl0[k] = f2bf(v - bf2f(hh));
                    }
                    #pragma unroll
                    for (int k = 0; k < 8; k++) {
                        float v = xp[(size_t)(k + 8) * HW];
                        short hh = f2bf(v); vh1[k] = hh; vl1[k] = f2bf(v - bf2f(hh));
                    }
                }
            }
            int bo = hp * BPAD + half * 16;
            *(short8*)&Bh_hi[bo]     = vh0;
            *(short8*)&Bh_hi[bo + 8] = vh1;
            *(short8*)&Bh_lo[bo]     = vl0;
            *(short8*)&Bh_lo[bo + 8] = vl1;
        }
        __syncthreads();   // hood visible; NO more barriers for 9 taps

        #pragma unroll
        for (int tap = 0; tap < 9; ++tap) {
            const int tp = tap & 1;          // hi set holding this tap's A
            const int dy = tap / 3, dx = tap - dy * 3;   // 0..2
            // ---- A-lo for CURRENT tap (used only in pass 3 -> latency
            //      covered by pass 1/2 MFMAs) ----
            {
                const size_t goff = (size_t)(ch * 9 + tap) * 4096;
                #pragma unroll
                for (int mt = 0; mt < 4; mt++)
                    pal[mt] = *(const short8*)(wl_lane + goff + mt * 512);
            }
            short8 bh[4], bl[4];
            #pragma unroll
            for (int nt = 0; nt < 4; nt++) {
                int n = wn * 64 + nt * 16 + l15;
                int ro = ((((n >> 4) + dy) * 18) + (n & 15) + dx) * BPAD + quad * 8;
                bh[nt] = *(const short8*)&Bh_hi[ro];
                bl[nt] = *(const short8*)&Bh_lo[ro];
            }
            // prefetch A-hi(tap+1) into the other set (hidden under MFMAs)
            if (tap < 8) {
                const int nx = (tap + 1) & 1;
                const size_t goff = (size_t)(ch * 9 + tap + 1) * 4096;
                #pragma unroll
                for (int mt = 0; mt < 4; mt++)
                    pah[nx][mt] = *(const short8*)(wh_lane + goff + mt * 512);
            }
            __builtin_amdgcn_s_setprio(1);
            // pass 1: hi x hi -- 16 independent MFMAs
            #pragma unroll
            for (int mt = 0; mt < 4; mt++)
                #pragma unroll
                for (int nt = 0; nt < 4; nt++)
                    acc[mt][nt] = __builtin_amdgcn_mfma_f32_16x16x32_bf16(pah[tp][mt], bh[nt], acc[mt][nt], 0, 0, 0);
            // pass 2: hi x lo
            #pragma unroll
            for (int mt = 0; mt < 4; mt++)
                #pragma unroll
                for (int nt = 0; nt < 4; nt++)
                    acc[mt][nt] = __builtin_amdgcn_mfma_f32_16x16x32_bf16(pah[tp][mt], bl[nt], acc[mt][nt], 0, 0, 0);
            // pass 3: lo x hi
            #pragma unroll
            for (int mt = 0; mt < 4; mt++)
                #pragma unroll
                for (int nt = 0; nt < 4; nt++)
                    acc[mt][nt] = __builtin_amdgcn_mfma_f32_16x16x32_bf16(pal[mt], bh[nt], acc[mt][nt], 0, 0, 0);
            __builtin_amdgcn_s_setprio(0);
            // tap 8: prefetch next chunk's tap 0 A-hi into set 0 AFTER the
            // MFMAs (WAR-safe in program order; latency covered by the
            // chunk-boundary hood staging)
            if (tap == 8 && c < h.chunks - 1) {
                const size_t goff = (size_t)((ch + 1) * 9) * 4096;
                #pragma unroll
                for (int mt = 0; mt < 4; mt++)
                    pah[0][mt] = *(const short8*)(wh_lane + goff + mt * 512);
            }
        }
    }

    // ---- epilogue: y += acc (+bias on kb==0); fused objectness partial dot --
    for (int idx = tid; idx < 384; idx += 256) {
        int a = idx >> 7, m = idx & 127;
        wobj[a][m] = h.w1[(size_t)(a * 85 + 4) * C + co0 + m];
    }
    __syncthreads();
    const bool ksplit = (h.kmask != 0);
    #pragma unroll
    for (int nt = 0; nt < 4; nt++) {
        int n = wn * 64 + nt * 16 + l15;
        int py = py0 + (n >> 4), px = px0 + (n & 15);
        if (px < W) {
            int p = py * W + px;
            float s0 = 0.f, s1 = 0.f, s2 = 0.f;
            #pragma unroll
            for (int mt = 0; mt < 4; mt++) {
                #pragma unroll
                for (int r = 0; r < 4; r++) {
                    int m = wm * 64 + mt * 16 + quad * 4 + r;
                    int co = co0 + m;
                    float yv = acc[mt][nt][r] + (kb == 0 ? h.bias[co] : 0.f);
                    if (ksplit) atomicAdd(&h.y[(size_t)co * HW + p], yv);
                    else        h.y[(size_t)co * HW + p] = yv;
                    s0 = fmaf(yv, wobj[0][m], s0);
                    s1 = fmaf(yv, wobj[1][m], s1);
                    s2 = fmaf(yv, wobj[2][m], s2);
                }
            }
            atomicAdd(&logits[h.lbase + p], s0);
            atomicAdd(&logits[h.lbase + HW + p], s1);
            atomicAdd(&logits[h.lbase + 2 * HW + p], s2);
        }
    }
}

// ---------------- keys: logits -> sigmoid -> sort key + histogram ------------
__global__ __launch_bounds__(256) void keys_kernel(
    const float* __restrict__ logits,
    const float* __restrict__ b10, const float* __restrict__ b11, const float* __restrict__ b12,
    u64* __restrict__ keys, u32* __restrict__ hist)
{
    int i = blockIdx.x * 256 + threadIdx.x;
    if (i >= NBOX) return;
    float bias;
    if (i < 4800)       bias = b10[(i / 1600) * 85 + 4];
    else if (i < 24000) bias = b11[((i - 4800) / 6400) * 85 + 4];
    else                bias = b12[((i - 24000) / 25600) * 85 + 4];
    float s = 1.0f / (1.0f + expf(-(logits[i] + bias)));
    u64 k = ((u64)__float_as_uint(s) << 32) | (u64)(0xFFFFFFFFu - (u32)i);
    keys[i] = k;
    atomicAdd(&hist[(u32)(k >> 48)], 1u);
}

// ---------------- top-256 selection ----------------
__global__ __launch_bounds__(256) void select_kernel(const u32* __restrict__ hist,
                                                     u32* __restrict__ meta)
{
    __shared__ u32 csum[256];
    int t = threadIdx.x;
    // R9: uint4 reads (4x fewer serial loads on the 1KB per-thread scan)
    const uint4* h4 = (const uint4*)(hist + t * 256);
    u32 s = 0;
    #pragma unroll 8
    for (int i = 0; i < 64; i++) { uint4 v = h4[i]; s += v.x + v.y + v.z + v.w; }
    csum[t] = s;
    __syncthreads();
    if (t == 0) {
        u32 cum = 0; int chunk = 255;
        for (; chunk > 0; chunk--) {
            if (cum + csum[chunk] >= 256u) break;
            cum += csum[chunk];
        }
        int B = chunk * 256;
        u32 cumAbove = cum;
        for (int bb = chunk * 256 + 255; bb >= chunk * 256; bb--) {
            u32 h = hist[bb];
            if (cumAbove + h >= 256u) { B = bb; break; }
            cumAbove += h;
        }
        meta[0] = (u32)B;
        meta[1] = cumAbove;
    }
}

__global__ __launch_bounds__(256) void compact_kernel(
    const u64* __restrict__ keys, int n, const u32* __restrict__ meta,
    u64* __restrict__ cand, u32* __restrict__ count)
{
    int i = blockIdx.x * blockDim.x + threadIdx.x;
    if (i < n) {
        u64 k = keys[i];
        if ((u32)(k >> 48) >= meta[0]) {
            u32 pos = atomicAdd(count, 1u);
            if (pos < CAND_CAP) cand[pos] = k;
        }
    }
}

// Dynamic bitonic size — sort next_pow2(n) >= 256 instead of always 4096.
__global__ __launch_bounds__(1024) void sort_select_kernel(
    const u64* __restrict__ cand, const u32* __restrict__ meta,
    u32* __restrict__ sel)
{
    __shared__ u64 sk[CAND_CAP];
    int n = (int)meta[2];
    if (n > CAND_CAP) n = CAND_CAP;
    int P = 256;
    while (P < n) P <<= 1;          // 256 <= P <= 4096, uniform across block
    for (int i = threadIdx.x; i < P; i += 1024)
        sk[i] = (i < n) ? cand[i] : 0ull;
    __syncthreads();
    for (int k = 2; k <= P; k <<= 1) {
        for (int j = k >> 1; j > 0; j >>= 1) {
            for (int i = threadIdx.x; i < P; i += 1024) {
                int ixj = i ^ j;
                if (ixj > i) {
                    u64 a = sk[i], c = sk[ixj];
                    bool sw = ((i & k) == 0) ? (a > c) : (a < c);
                    if (sw) { sk[i] = c; sk[ixj] = a; }
                }
            }
            __syncthreads();
        }
    }
    if (threadIdx.x < 256) {
        u64 k = sk[P - 1 - threadIdx.x];
        sel[threadIdx.x] = 0xFFFFFFFFu - (u32)(k & 0xFFFFFFFFull);
    }
}

// ---------------- final: full 85-ch 1x1 conv + decode for the 256 winners ---
__global__ __launch_bounds__(256) void final_kernel(
    const float* __restrict__ y0, const float* __restrict__ y1, const float* __restrict__ y2,
    const float* __restrict__ w10, const float* __restrict__ w11, const float* __restrict__ w12,
    const float* __restrict__ b10, const float* __restrict__ b11, const float* __restrict__ b12,
    const u32* __restrict__ sel, float* __restrict__ out)
{
    int b = blockIdx.x;
    u32 bi = sel[b];
    const float *y, *w1, *b1;
    int C, H, W, base; float ratio;
    float anchs[6];
    if (bi < 4800u) {
        y = y0; w1 = w10; b1 = b10; C = 1024; H = 40; W = 40; base = 0; ratio = 32.f;
        anchs[0]=116.f; anchs[1]=90.f; anchs[2]=156.f; anchs[3]=198.f; anchs[4]=373.f; anchs[5]=326.f;
    } else if (bi < 24000u) {
        y = y1; w1 = w11; b1 = b11; C = 512; H = 80; W = 80; base = 4800; ratio = 16.f;
        anchs[0]=30.f; anchs[1]=61.f; anchs[2]=62.f; anchs[3]=45.f; anchs[4]=59.f; anchs[5]=119.f;
    } else {
        y = y2; w1 = w12; b1 = b12; C = 256; H = 160; W = 160; base = 24000; ratio = 8.f;
        anchs[0]=10.f; anchs[1]=13.f; anchs[2]=16.f; anchs[3]=30.f; anchs[4]=33.f; anchs[5]=23.f;
    }
    int HW = H * W;
    int r = (int)bi - base;
    int a = r / HW, p = r % HW;
    __shared__ float ys[256];
    int c = threadIdx.x;
    float acc = 0.f;
    const float* wrow = w1 + (size_t)(a * 85 + (c < 85 ? c : 0)) * C;
    for (int ci0 = 0; ci0 < C; ci0 += 256) {
        __syncthreads();
        ys[c] = y[(size_t)(ci0 + c) * HW + p];
        __syncthreads();
        if (c < 85)
            for (int ci = 0; ci < 256; ci++) acc = fmaf(ys[ci], wrow[ci0 + ci], acc);
    }
    if (c < 85) {
        float v = acc + b1[a * 85 + c];
        float s = 1.0f / (1.0f + expf(-v));
        int py = p / W, px = p - (p / W) * W;
        float o;
        if (c == 0)      o = (s * 2.0f - 0.5f + (float)px) * ratio;
        else if (c == 1) o = (s * 2.0f - 0.5f + (float)py) * ratio;
        else if (c == 2) { float t = s * 2.0f; o = t * t * anchs[a * 2]; }
        else if (c == 3) { float t = s * 2.0f; o = t * t * anchs[a * 2 + 1]; }
        else             o = s;
        out[(size_t)b * 85 + c] = o;
    }
}

// ---------------- launch ----------------
extern "C" void kernel_launch(void* const* d_in, const int* in_sizes, int n_in,
                              void* d_out, int out_size, void* d_ws, size_t ws_size,
                              hipStream_t stream)
{
    const float* feat0 = (const float*)d_in[0];   // (256,160,160)
    const float* feat1 = (const float*)d_in[1];   // (512,80,80)
    const float* feat2 = (const float*)d_in[2];   // (1024,40,40)
    const float* w3_0 = (const float*)d_in[3];  const float* b3_0 = (const float*)d_in[4];
    const float* w1_0 = (const float*)d_in[5];  const float* b1_0 = (const float*)d_in[6];
    const float* w3_1 = (const float*)d_in[7];  const float* b3_1 = (const float*)d_in[8];
    const float* w1_1 = (const float*)d_in[9];  const float* b1_1 = (const float*)d_in[10];
    const float* w3_2 = (const float*)d_in[11]; const float* b3_2 = (const float*)d_in[12];
    const float* w1_2 = (const float*)d_in[13]; const float* b1_2 = (const float*)d_in[14];

    char* ws = (char*)d_ws;
    short* wth0 = (short*)(ws + OFF_WTH0);
    short* wth1 = (short*)(ws + OFF_WTH1);
    short* wth2 = (short*)(ws + OFF_WTH2);
    short* wtl0 = (short*)(ws + OFF_WTL0);
    short* wtl1 = (short*)(ws + OFF_WTL1);
    short* wtl2 = (short*)(ws + OFF_WTL2);
    float* y0   = (float*)(ws + OFF_Y0);
    float* y1   = (float*)(ws + OFF_Y1);
    float* y2   = (float*)(ws + OFF_Y2);
    u64*   keys = (u64*)  (ws + OFF_KEYS);
    u32*   hist = (u32*)  (ws + OFF_HIST);
    u32*   meta = (u32*)  (ws + OFF_META);
    float* logits = (float*)(ws + OFF_LOG);
    u64*   cand = (u64*)  (ws + OFF_CAND);
    u32*   sel  = (u32*)  (ws + OFF_SEL);

    const int use_xt = (ws_size >= NEED_FULL) ? 1 : 0;
    short* xth0 = (short*)(ws + OFF_XTH0);
    short* xth1 = (short*)(ws + OFF_XTH1);
    short* xth2 = (short*)(ws + OFF_XTH2);
    short* xtl0 = (short*)(ws + OFF_XTL0);
    short* xtl1 = (short*)(ws + OFF_XTL1);
    short* xtl2 = (short*)(ws + OFF_XTL2);

    hipMemsetAsync(ws + OFF_HIST, 0, MEMSET_LEN, stream);
    hipMemsetAsync(ws + OFF_Y0, 0, Y01_LEN, stream);   // y0,y1 accumulate via atomics

    // weight transforms (fragment-ordered)
    prep_w_kernel<<<4096, 256, 0, stream>>>(w3_0, wth0, wtl0, 1024);
    prep_w_kernel<<<1024, 256, 0, stream>>>(w3_1, wth1, wtl1, 512);
    prep_w_kernel<<<256,  256, 0, stream>>>(w3_2, wth2, wtl2, 256);

    // input transpose + bf16 split
    if (use_xt) {
        PrepX p0 = {feat2, xth0, xtl0, 1024, 1600,  0,    50};
        PrepX p1 = {feat1, xth1, xtl1, 512,  6400,  1600, 200};
        PrepX p2 = {feat0, xth2, xtl2, 256,  25600, 4800, 800};
        prep_x_kernel<<<11200, 256, 0, stream>>>(p0, p1, p2);
    }

    // fused 3-head 3x3 conv (+ objectness partials), K-split for balance:
    // head0: 8 co x 4 kb x 15 sp = 480; head1: 4 x 2 x 50 = 400; head2: 2 x 1 x 200 = 400
    ConvHead h0 = {feat2, xth0, xtl0, wth0, wtl0, b3_0, w1_0, y0, 1024, 40,  40,  3,  7, 3, 3, 2, 8, 0,   0};
    ConvHead h1 = {feat1, xth1, xtl1, wth1, wtl1, b3_1, w1_1, y1, 512,  80,  80,  5,  3, 2, 1, 1, 8, 480, 4800};
    ConvHead h2 = {feat0, xth2, xtl2, wth2, wtl2, b3_2, w1_2, y2, 256,  160, 160, 10, 1, 1, 0, 0, 8, 880, 24000};
    conv3x3_mfma<<<1280, 256, 0, stream>>>(h0, h1, h2, logits, use_xt);

    // keys + histogram from logits
    keys_kernel<<<(NBOX + 255) / 256, 256, 0, stream>>>(logits, b1_0, b1_1, b1_2, keys, hist);

    // top-256
    select_kernel<<<1, 256, 0, stream>>>(hist, meta);
    compact_kernel<<<(NBOX + 255) / 256, 256, 0, stream>>>(keys, NBOX, meta, cand, meta + 2);
    sort_select_kernel<<<1, 1024, 0, stream>>>(cand, meta, sel);

    // full 85-channel compute + decode for winners only
    final_kernel<<<256, 256, 0, stream>>>(y0, y1, y2, w1_0, w1_1, w1_2,
                                          b1_0, b1_1, b1_2, sel, (float*)d_out);
}

// Round 6
// 787.184 us; speedup vs baseline: 1.0599x; 1.0599x over previous
//
#include <hip/hip_runtime.h>
#include <cstdint>
#include <cstddef>

typedef unsigned long long u64;
typedef unsigned int u32;
typedef __attribute__((ext_vector_type(8))) short short8;
typedef __attribute__((ext_vector_type(4))) float f32x4;

#define NBOX 100800
#define CAND_CAP 4096
#define BPAD 36   // hood pixel stride (shorts)

// ---------------- workspace layout (bytes) ----------------
#define OFF_WTH0 ((size_t)0)
#define OFF_WTH1 ((size_t)18874368)
#define OFF_WTH2 ((size_t)23592960)
#define OFF_WTL0 ((size_t)24772608)
#define OFF_WTL1 ((size_t)43646976)
#define OFF_WTL2 ((size_t)48365568)
#define OFF_Y0   ((size_t)49545216)
#define OFF_Y1   ((size_t)56098816)
#define OFF_Y2   ((size_t)69206016)
#define OFF_KEYS ((size_t)95420416)
#define OFF_HIST ((size_t)96226816)   // 262144
#define OFF_META ((size_t)96488960)   // 64
#define OFF_LOG  ((size_t)96489024)   // 100800*4 = 403200 (zeroed with hist+meta)
#define OFF_CAND ((size_t)96892224)   // 32768
#define OFF_SEL  ((size_t)96924992)   // 1024
#define OFF_XTH0 ((size_t)96926016)
#define OFF_XTH1 ((size_t)100202816)
#define OFF_XTH2 ((size_t)106756416)
#define OFF_XTL0 ((size_t)119863616)
#define OFF_XTL1 ((size_t)123140416)
#define OFF_XTL2 ((size_t)129694016)
#define NEED_FULL ((size_t)142801216)
#define MEMSET_LEN ((size_t)(262144 + 64 + 403200))
#define Y01_LEN   ((size_t)(6553600 + 13107200))   // y0 + y1 zeroed for K-split atomics

// ---------------- bf16 helpers (RNE, finite inputs) ----------------
__device__ __forceinline__ short f2bf(float f) {
    u32 u = __float_as_uint(f);
    u = (u + 0x7fffu + ((u >> 16) & 1u)) >> 16;
    return (short)u;
}
__device__ __forceinline__ float bf2f(short h) {
    return __uint_as_float(((u32)(unsigned short)h) << 16);
}

// ---- weight prep: (co,ci,3,3) f32 -> fragment-ordered bf16 hi/lo ----
// Layout: [my(co/128)][ch(ci/32)][tap(9)][m(128)][ci(32)]
// Per (wm,mt) MFMA A-fragment = one contiguous, aligned 1KB block.
__global__ __launch_bounds__(256) void prep_w_kernel(
    const float* __restrict__ w, short* __restrict__ wh, short* __restrict__ wl, int C)
{
    __shared__ float ws_[2304];
    int chunks256 = C >> 8;
    int co = blockIdx.x / chunks256;
    int ci0 = (blockIdx.x % chunks256) << 8;
    size_t base = ((size_t)co * C + ci0) * 9;
    for (int idx = threadIdx.x; idx < 2304; idx += 256) ws_[idx] = w[base + idx];
    __syncthreads();
    int my = co >> 7, m = co & 127;
    int chunksW = C >> 5;
    for (int idx = threadIdx.x; idx < 2304; idx += 256) {
        int tap = idx >> 8, ci = idx & 255;
        float v = ws_[ci * 9 + tap];
        short h = f2bf(v);
        short l = f2bf(v - bf2f(h));
        int gci = ci0 + ci;
        int ch = gci >> 5, ciw = gci & 31;
        size_t o = ((((size_t)my * chunksW + ch) * 9 + tap) * 128 + m) * 32 + ciw;
        wh[o] = h; wl[o] = l;
    }
}

// ---------------- input prep: [C][HW] f32 -> [pix][C] bf16 hi/lo (transpose) --
struct PrepX { const float* x; short* xh; short* xl; int C, HW, bbase, ptiles; };

__global__ __launch_bounds__(256) void prep_x_kernel(PrepX p0, PrepX p1, PrepX p2)
{
    PrepX p = (blockIdx.x >= (u32)p2.bbase) ? p2 :
              (blockIdx.x >= (u32)p1.bbase) ? p1 : p0;
    int local = blockIdx.x - p.bbase;
    int pt = local % p.ptiles, ct = local / p.ptiles;
    __shared__ short th[32][34];
    __shared__ short tl[32][34];
    for (int idx = threadIdx.x; idx < 1024; idx += 256) {
        int ci = idx >> 5, px = idx & 31;
        float v = p.x[(size_t)(ct * 32 + ci) * p.HW + pt * 32 + px];
        short h = f2bf(v);
        th[ci][px] = h;
        tl[ci][px] = f2bf(v - bf2f(h));
    }
    __syncthreads();
    for (int idx = threadIdx.x; idx < 1024; idx += 256) {
        int px = idx >> 5, ci = idx & 31;
        size_t o = (size_t)(pt * 32 + px) * p.C + ct * 32 + ci;
        p.xh[o] = th[ci][px];
        p.xl[o] = tl[ci][px];
    }
}

// ------- fused 3-head 3x3 conv, bf16 MFMA hi/lo 3-pass, tap-reuse hood -------
// R10: barrier-free tap loop (R8) + HALVED per-wave tile for real occupancy:
//  - block tile 128co x 64px (4 rows x 16 cols); wave = 64co x 32px
//  - acc[4][2] = 32 VGPR (was 64) -> natural footprint ~130 -> 3 blocks/CU
//    (12 waves) with launch_bounds(256,3) SLACK, no spill (R9 lesson)
//  - per-wave-tap LDS reads: 4 ds_read_b128 (was 8) -> LDS pipe well under
//    MFMA demand; more waves to overlap the lgkmcnt waits
//  - A-hi double-set prefetch one tap ahead; A-lo single-set (pass-2 use)
//  - MFMA passes ordered {hi*hi(bh), lo*hi(bh), hi*lo(bl)}: 8 indep chains
// K-split retained: every block does exactly 8 chunks; head0 4-way, head1
// 2-way over the reduction (partial y via atomicAdd, y pre-zeroed).
struct ConvHead {
    const float* x; const short* xh; const short* xl;
    const short* wh; const short* wl; const float* bias;
    const float* w1; float* y;
    int C, H, W, sx, nco_mask, nco_shift, kmask, kshift, chunks, bbase, lbase;
};

__global__ __launch_bounds__(256, 3) void conv3x3_mfma(
    ConvHead h0, ConvHead h1, ConvHead h2, float* __restrict__ logits, int use_xt)
{
    ConvHead h = (blockIdx.x >= (u32)h2.bbase) ? h2 :
                 (blockIdx.x >= (u32)h1.bbase) ? h1 : h0;
    const int local = blockIdx.x - h.bbase;
    const int my = local & h.nco_mask;
    const int rest = local >> h.nco_shift;
    const int kb = rest & h.kmask;
    const int sp = rest >> h.kshift;
    const int ty = sp / h.sx;
    const int tx = sp - ty * h.sx;
    const int py0 = ty * 4, px0 = tx * 16;     // 4-row x 16-col block tile
    const int co0 = my * 128;
    const int C = h.C, H = h.H, W = h.W, HW = H * W;

    const int tid = threadIdx.x;
    const int lane = tid & 63;
    const int wave = tid >> 6;
    const int quad = lane >> 4;
    const int l15 = lane & 15;
    const int wm = wave >> 1, wn = wave & 1;   // wm: co half, wn: row pair

    __shared__ short Bh_hi[108 * BPAD];   // 6 x 18 pixel hood x 32 ch
    __shared__ short Bh_lo[108 * BPAD];
    __shared__ float wobj[3][128];

    f32x4 acc[4][2];
    #pragma unroll
    for (int i = 0; i < 4; i++)
        #pragma unroll
        for (int j = 0; j < 2; j++) acc[i][j] = (f32x4){0.f, 0.f, 0.f, 0.f};

    const int chunksW = C >> 5;
    // per-lane base into fragment-ordered weights: frag (g, mt) at
    // lane_ptr + g*4096 + mt*512
    const size_t mybase = (size_t)my * chunksW * 9 * 4096;
    const int lane_off = wm * 2048 + l15 * 32 + quad * 8;
    const short* __restrict__ wh_lane = h.wh + mybase + lane_off;
    const short* __restrict__ wl_lane = h.wl + mybase + lane_off;
    const int ch0 = kb * h.chunks;

    // A-hi prefetch double-set (by tap parity); A-lo single-set per tap
    short8 pah[2][4], pal[4];

    // prologue: load A-hi frags for global tap 0
    {
        const size_t goff = (size_t)(ch0 * 9) * 4096;
        #pragma unroll
        for (int mt = 0; mt < 4; mt++)
            pah[0][mt] = *(const short8*)(wh_lane + goff + mt * 512);
    }

    for (int c = 0; c < h.chunks; ++c) {
        const int ch = ch0 + c;
        const int ci0 = ch << 5;
        __syncthreads();   // prev chunk B reads fully consumed
        // ---- stage hood: 108 pixels x 32 channels, hi/lo, zero-padded ----
        // 216 slots over 256 threads: single pass
        if (tid < 216) {
            int hp = tid >> 1, half = tid & 1;
            int hy = hp / 18, hx = hp - hy * 18;
            int gy = py0 - 1 + hy, gx = px0 - 1 + hx;
            short8 vh0 = {0,0,0,0,0,0,0,0}, vh1 = {0,0,0,0,0,0,0,0};
            short8 vl0 = {0,0,0,0,0,0,0,0}, vl1 = {0,0,0,0,0,0,0,0};
            if (gy >= 0 && gy < H && gx >= 0 && gx < W) {
                if (use_xt) {
                    size_t ro = (size_t)(gy * W + gx) * C + ci0 + half * 16;
                    const short* ph = h.xh + ro;
                    const short* pl = h.xl + ro;
                    vh0 = *(const short8*)ph; vh1 = *(const short8*)(ph + 8);
                    vl0 = *(const short8*)pl; vl1 = *(const short8*)(pl + 8);
                } else {
                    const float* xp = h.x + (size_t)(ci0 + half * 16) * HW + gy * W + gx;
                    #pragma unroll
                    for (int k = 0; k < 8; k++) {
                        float v = xp[(size_t)k * HW];
                        short hh = f2bf(v); vh0[k] = hh; vl0[k] = f2bf(v - bf2f(hh));
                    }
                    #pragma unroll
                    for (int k = 0; k < 8; k++) {
                        float v = xp[(size_t)(k + 8) * HW];
                        short hh = f2bf(v); vh1[k] = hh; vl1[k] = f2bf(v - bf2f(hh));
                    }
                }
            }
            int bo = hp * BPAD + half * 16;
            *(short8*)&Bh_hi[bo]     = vh0;
            *(short8*)&Bh_hi[bo + 8] = vh1;
            *(short8*)&Bh_lo[bo]     = vl0;
            *(short8*)&Bh_lo[bo + 8] = vl1;
        }
        __syncthreads();   // hood visible; NO more barriers for 9 taps

        #pragma unroll
        for (int tap = 0; tap < 9; ++tap) {
            const int tp = tap & 1;          // hi set holding this tap's A
            const int dy = tap / 3, dx = tap - dy * 3;   // 0..2
            // ---- A-lo for CURRENT tap (used only in pass 2) ----
            {
                const size_t goff = (size_t)(ch * 9 + tap) * 4096;
                #pragma unroll
                for (int mt = 0; mt < 4; mt++)
                    pal[mt] = *(const short8*)(wl_lane + goff + mt * 512);
            }
            short8 bh[2], bl[2];
            #pragma unroll
            for (int nt = 0; nt < 2; nt++) {
                // wave's pixel (nt): row = wn*2 + nt, col = l15
                int ro = ((wn * 2 + nt + dy) * 18 + l15 + dx) * BPAD + quad * 8;
                bh[nt] = *(const short8*)&Bh_hi[ro];
                bl[nt] = *(const short8*)&Bh_lo[ro];
            }
            // prefetch A-hi(tap+1) into the other set (hidden under MFMAs)
            if (tap < 8) {
                const int nx = (tap + 1) & 1;
                const size_t goff = (size_t)(ch * 9 + tap + 1) * 4096;
                #pragma unroll
                for (int mt = 0; mt < 4; mt++)
                    pah[nx][mt] = *(const short8*)(wh_lane + goff + mt * 512);
            }
            __builtin_amdgcn_s_setprio(1);
            // pass 1: hi x hi -- 8 independent MFMAs
            #pragma unroll
            for (int mt = 0; mt < 4; mt++)
                #pragma unroll
                for (int nt = 0; nt < 2; nt++)
                    acc[mt][nt] = __builtin_amdgcn_mfma_f32_16x16x32_bf16(pah[tp][mt], bh[nt], acc[mt][nt], 0, 0, 0);
            // pass 2: lo x hi (bh still live; pal latency covered by pass 1)
            #pragma unroll
            for (int mt = 0; mt < 4; mt++)
                #pragma unroll
                for (int nt = 0; nt < 2; nt++)
                    acc[mt][nt] = __builtin_amdgcn_mfma_f32_16x16x32_bf16(pal[mt], bh[nt], acc[mt][nt], 0, 0, 0);
            // pass 3: hi x lo
            #pragma unroll
            for (int mt = 0; mt < 4; mt++)
                #pragma unroll
                for (int nt = 0; nt < 2; nt++)
                    acc[mt][nt] = __builtin_amdgcn_mfma_f32_16x16x32_bf16(pah[tp][mt], bl[nt], acc[mt][nt], 0, 0, 0);
            __builtin_amdgcn_s_setprio(0);
            // tap 8: prefetch next chunk's tap 0 A-hi into set 0 AFTER the
            // MFMAs (WAR-safe in program order; latency covered by the
            // chunk-boundary hood staging)
            if (tap == 8 && c < h.chunks - 1) {
                const size_t goff = (size_t)((ch + 1) * 9) * 4096;
                #pragma unroll
                for (int mt = 0; mt < 4; mt++)
                    pah[0][mt] = *(const short8*)(wh_lane + goff + mt * 512);
            }
        }
    }

    // ---- epilogue: y += acc (+bias on kb==0); fused objectness partial dot --
    for (int idx = tid; idx < 384; idx += 256) {
        int a = idx >> 7, m = idx & 127;
        wobj[a][m] = h.w1[(size_t)(a * 85 + 4) * C + co0 + m];
    }
    __syncthreads();
    const bool ksplit = (h.kmask != 0);
    #pragma unroll
    for (int nt = 0; nt < 2; nt++) {
        int py = py0 + wn * 2 + nt, px = px0 + l15;
        if (px < W) {
            int p = py * W + px;
            float s0 = 0.f, s1 = 0.f, s2 = 0.f;
            #pragma unroll
            for (int mt = 0; mt < 4; mt++) {
                #pragma unroll
                for (int r = 0; r < 4; r++) {
                    int m = wm * 64 + mt * 16 + quad * 4 + r;
                    int co = co0 + m;
                    float yv = acc[mt][nt][r] + (kb == 0 ? h.bias[co] : 0.f);
                    if (ksplit) atomicAdd(&h.y[(size_t)co * HW + p], yv);
                    else        h.y[(size_t)co * HW + p] = yv;
                    s0 = fmaf(yv, wobj[0][m], s0);
                    s1 = fmaf(yv, wobj[1][m], s1);
                    s2 = fmaf(yv, wobj[2][m], s2);
                }
            }
            atomicAdd(&logits[h.lbase + p], s0);
            atomicAdd(&logits[h.lbase + HW + p], s1);
            atomicAdd(&logits[h.lbase + 2 * HW + p], s2);
        }
    }
}

// ---------------- keys: logits -> sigmoid -> sort key + histogram ------------
__global__ __launch_bounds__(256) void keys_kernel(
    const float* __restrict__ logits,
    const float* __restrict__ b10, const float* __restrict__ b11, const float* __restrict__ b12,
    u64* __restrict__ keys, u32* __restrict__ hist)
{
    int i = blockIdx.x * 256 + threadIdx.x;
    if (i >= NBOX) return;
    float bias;
    if (i < 4800)       bias = b10[(i / 1600) * 85 + 4];
    else if (i < 24000) bias = b11[((i - 4800) / 6400) * 85 + 4];
    else                bias = b12[((i - 24000) / 25600) * 85 + 4];
    float s = 1.0f / (1.0f + expf(-(logits[i] + bias)));
    u64 k = ((u64)__float_as_uint(s) << 32) | (u64)(0xFFFFFFFFu - (u32)i);
    keys[i] = k;
    atomicAdd(&hist[(u32)(k >> 48)], 1u);
}

// ---------------- top-256 selection ----------------
__global__ __launch_bounds__(256) void select_kernel(const u32* __restrict__ hist,
                                                     u32* __restrict__ meta)
{
    __shared__ u32 csum[256];
    int t = threadIdx.x;
    const uint4* h4 = (const uint4*)(hist + t * 256);
    u32 s = 0;
    #pragma unroll 8
    for (int i = 0; i < 64; i++) { uint4 v = h4[i]; s += v.x + v.y + v.z + v.w; }
    csum[t] = s;
    __syncthreads();
    if (t == 0) {
        u32 cum = 0; int chunk = 255;
        for (; chunk > 0; chunk--) {
            if (cum + csum[chunk] >= 256u) break;
            cum += csum[chunk];
        }
        int B = chunk * 256;
        u32 cumAbove = cum;
        for (int bb = chunk * 256 + 255; bb >= chunk * 256; bb--) {
            u32 h = hist[bb];
            if (cumAbove + h >= 256u) { B = bb; break; }
            cumAbove += h;
        }
        meta[0] = (u32)B;
        meta[1] = cumAbove;
    }
}

__global__ __launch_bounds__(256) void compact_kernel(
    const u64* __restrict__ keys, int n, const u32* __restrict__ meta,
    u64* __restrict__ cand, u32* __restrict__ count)
{
    int i = blockIdx.x * blockDim.x + threadIdx.x;
    if (i < n) {
        u64 k = keys[i];
        if ((u32)(k >> 48) >= meta[0]) {
            u32 pos = atomicAdd(count, 1u);
            if (pos < CAND_CAP) cand[pos] = k;
        }
    }
}

// Dynamic bitonic size — sort next_pow2(n) >= 256 instead of always 4096.
__global__ __launch_bounds__(1024) void sort_select_kernel(
    const u64* __restrict__ cand, const u32* __restrict__ meta,
    u32* __restrict__ sel)
{
    __shared__ u64 sk[CAND_CAP];
    int n = (int)meta[2];
    if (n > CAND_CAP) n = CAND_CAP;
    int P = 256;
    while (P < n) P <<= 1;          // 256 <= P <= 4096, uniform across block
    for (int i = threadIdx.x; i < P; i += 1024)
        sk[i] = (i < n) ? cand[i] : 0ull;
    __syncthreads();
    for (int k = 2; k <= P; k <<= 1) {
        for (int j = k >> 1; j > 0; j >>= 1) {
            for (int i = threadIdx.x; i < P; i += 1024) {
                int ixj = i ^ j;
                if (ixj > i) {
                    u64 a = sk[i], c = sk[ixj];
                    bool sw = ((i & k) == 0) ? (a > c) : (a < c);
                    if (sw) { sk[i] = c; sk[ixj] = a; }
                }
            }
            __syncthreads();
        }
    }
    if (threadIdx.x < 256) {
        u64 k = sk[P - 1 - threadIdx.x];
        sel[threadIdx.x] = 0xFFFFFFFFu - (u32)(k & 0xFFFFFFFFull);
    }
}

// ---------------- final: full 85-ch 1x1 conv + decode for the 256 winners ---
__global__ __launch_bounds__(256) void final_kernel(
    const float* __restrict__ y0, const float* __restrict__ y1, const float* __restrict__ y2,
    const float* __restrict__ w10, const float* __restrict__ w11, const float* __restrict__ w12,
    const float* __restrict__ b10, const float* __restrict__ b11, const float* __restrict__ b12,
    const u32* __restrict__ sel, float* __restrict__ out)
{
    int b = blockIdx.x;
    u32 bi = sel[b];
    const float *y, *w1, *b1;
    int C, H, W, base; float ratio;
    float anchs[6];
    if (bi < 4800u) {
        y = y0; w1 = w10; b1 = b10; C = 1024; H = 40; W = 40; base = 0; ratio = 32.f;
        anchs[0]=116.f; anchs[1]=90.f; anchs[2]=156.f; anchs[3]=198.f; anchs[4]=373.f; anchs[5]=326.f;
    } else if (bi < 24000u) {
        y = y1; w1 = w11; b1 = b11; C = 512; H = 80; W = 80; base = 4800; ratio = 16.f;
        anchs[0]=30.f; anchs[1]=61.f; anchs[2]=62.f; anchs[3]=45.f; anchs[4]=59.f; anchs[5]=119.f;
    } else {
        y = y2; w1 = w12; b1 = b12; C = 256; H = 160; W = 160; base = 24000; ratio = 8.f;
        anchs[0]=10.f; anchs[1]=13.f; anchs[2]=16.f; anchs[3]=30.f; anchs[4]=33.f; anchs[5]=23.f;
    }
    int HW = H * W;
    int r = (int)bi - base;
    int a = r / HW, p = r % HW;
    __shared__ float ys[256];
    int c = threadIdx.x;
    float acc = 0.f;
    const float* wrow = w1 + (size_t)(a * 85 + (c < 85 ? c : 0)) * C;
    for (int ci0 = 0; ci0 < C; ci0 += 256) {
        __syncthreads();
        ys[c] = y[(size_t)(ci0 + c) * HW + p];
        __syncthreads();
        if (c < 85)
            for (int ci = 0; ci < 256; ci++) acc = fmaf(ys[ci], wrow[ci0 + ci], acc);
    }
    if (c < 85) {
        float v = acc + b1[a * 85 + c];
        float s = 1.0f / (1.0f + expf(-v));
        int py = p / W, px = p - (p / W) * W;
        float o;
        if (c == 0)      o = (s * 2.0f - 0.5f + (float)px) * ratio;
        else if (c == 1) o = (s * 2.0f - 0.5f + (float)py) * ratio;
        else if (c == 2) { float t = s * 2.0f; o = t * t * anchs[a * 2]; }
        else if (c == 3) { float t = s * 2.0f; o = t * t * anchs[a * 2 + 1]; }
        else             o = s;
        out[(size_t)b * 85 + c] = o;
    }
}

// ---------------- launch ----------------
extern "C" void kernel_launch(void* const* d_in, const int* in_sizes, int n_in,
                              void* d_out, int out_size, void* d_ws, size_t ws_size,
                              hipStream_t stream)
{
    const float* feat0 = (const float*)d_in[0];   // (256,160,160)
    const float* feat1 = (const float*)d_in[1];   // (512,80,80)
    const float* feat2 = (const float*)d_in[2];   // (1024,40,40)
    const float* w3_0 = (const float*)d_in[3];  const float* b3_0 = (const float*)d_in[4];
    const float* w1_0 = (const float*)d_in[5];  const float* b1_0 = (const float*)d_in[6];
    const float* w3_1 = (const float*)d_in[7];  const float* b3_1 = (const float*)d_in[8];
    const float* w1_1 = (const float*)d_in[9];  const float* b1_1 = (const float*)d_in[10];
    const float* w3_2 = (const float*)d_in[11]; const float* b3_2 = (const float*)d_in[12];
    const float* w1_2 = (const float*)d_in[13]; const float* b1_2 = (const float*)d_in[14];

    char* ws = (char*)d_ws;
    short* wth0 = (short*)(ws + OFF_WTH0);
    short* wth1 = (short*)(ws + OFF_WTH1);
    short* wth2 = (short*)(ws + OFF_WTH2);
    short* wtl0 = (short*)(ws + OFF_WTL0);
    short* wtl1 = (short*)(ws + OFF_WTL1);
    short* wtl2 = (short*)(ws + OFF_WTL2);
    float* y0   = (float*)(ws + OFF_Y0);
    float* y1   = (float*)(ws + OFF_Y1);
    float* y2   = (float*)(ws + OFF_Y2);
    u64*   keys = (u64*)  (ws + OFF_KEYS);
    u32*   hist = (u32*)  (ws + OFF_HIST);
    u32*   meta = (u32*)  (ws + OFF_META);
    float* logits = (float*)(ws + OFF_LOG);
    u64*   cand = (u64*)  (ws + OFF_CAND);
    u32*   sel  = (u32*)  (ws + OFF_SEL);

    const int use_xt = (ws_size >= NEED_FULL) ? 1 : 0;
    short* xth0 = (short*)(ws + OFF_XTH0);
    short* xth1 = (short*)(ws + OFF_XTH1);
    short* xth2 = (short*)(ws + OFF_XTH2);
    short* xtl0 = (short*)(ws + OFF_XTL0);
    short* xtl1 = (short*)(ws + OFF_XTL1);
    short* xtl2 = (short*)(ws + OFF_XTL2);

    hipMemsetAsync(ws + OFF_HIST, 0, MEMSET_LEN, stream);
    hipMemsetAsync(ws + OFF_Y0, 0, Y01_LEN, stream);   // y0,y1 accumulate via atomics

    // weight transforms (fragment-ordered)
    prep_w_kernel<<<4096, 256, 0, stream>>>(w3_0, wth0, wtl0, 1024);
    prep_w_kernel<<<1024, 256, 0, stream>>>(w3_1, wth1, wtl1, 512);
    prep_w_kernel<<<256,  256, 0, stream>>>(w3_2, wth2, wtl2, 256);

    // input transpose + bf16 split
    if (use_xt) {
        PrepX p0 = {feat2, xth0, xtl0, 1024, 1600,  0,    50};
        PrepX p1 = {feat1, xth1, xtl1, 512,  6400,  1600, 200};
        PrepX p2 = {feat0, xth2, xtl2, 256,  25600, 4800, 800};
        prep_x_kernel<<<11200, 256, 0, stream>>>(p0, p1, p2);
    }

    // fused 3-head 3x3 conv (+ objectness partials), 128co x 64px tiles:
    // head0: 8 co x 4 kb x (10x3=30 sp) = 960
    // head1: 4 co x 2 kb x (20x5=100 sp) = 800   (bbase 960)
    // head2: 2 co x 1 kb x (40x10=400 sp) = 800  (bbase 1760)
    ConvHead h0 = {feat2, xth0, xtl0, wth0, wtl0, b3_0, w1_0, y0, 1024, 40,  40,  3,  7, 3, 3, 2, 8, 0,    0};
    ConvHead h1 = {feat1, xth1, xtl1, wth1, wtl1, b3_1, w1_1, y1, 512,  80,  80,  5,  3, 2, 1, 1, 8, 960,  4800};
    ConvHead h2 = {feat0, xth2, xtl2, wth2, wtl2, b3_2, w1_2, y2, 256,  160, 160, 10, 1, 1, 0, 0, 8, 1760, 24000};
    conv3x3_mfma<<<2560, 256, 0, stream>>>(h0, h1, h2, logits, use_xt);

    // keys + histogram from logits
    keys_kernel<<<(NBOX + 255) / 256, 256, 0, stream>>>(logits, b1_0, b1_1, b1_2, keys, hist);

    // top-256
    select_kernel<<<1, 256, 0, stream>>>(hist, meta);
    compact_kernel<<<(NBOX + 255) / 256, 256, 0, stream>>>(keys, NBOX, meta, cand, meta + 2);
    sort_select_kernel<<<1, 1024, 0, stream>>>(cand, meta, sel);

    // full 85-channel compute + decode for winners only
    final_kernel<<<256, 256, 0, stream>>>(y0, y1, y2, w1_0, w1_1, w1_2,
                                          b1_0, b1_1, b1_2, sel, (float*)d_out);
}

// Round 7
// 651.207 us; speedup vs baseline: 1.2812x; 1.2088x over previous
//
#include <hip/hip_runtime.h>
#include <cstdint>
#include <cstddef>

typedef unsigned long long u64;
typedef unsigned int u32;
typedef __attribute__((ext_vector_type(8))) short short8;
typedef __attribute__((ext_vector_type(4))) float f32x4;

#define NBOX 100800
#define CAND_CAP 4096
#define BPAD 36   // hood pixel stride (shorts)

// ---------------- workspace layout (bytes) ----------------
#define OFF_WTH0 ((size_t)0)
#define OFF_WTH1 ((size_t)18874368)
#define OFF_WTH2 ((size_t)23592960)
#define OFF_WTL0 ((size_t)24772608)
#define OFF_WTL1 ((size_t)43646976)
#define OFF_WTL2 ((size_t)48365568)
#define OFF_Y0   ((size_t)49545216)
#define OFF_Y1   ((size_t)56098816)
#define OFF_Y2   ((size_t)69206016)
#define OFF_KEYS ((size_t)95420416)
#define OFF_HIST ((size_t)96226816)   // 262144
#define OFF_META ((size_t)96488960)   // 64
#define OFF_LOG  ((size_t)96489024)   // 100800*4 = 403200
#define OFF_CAND ((size_t)96892224)   // 32768
#define OFF_SEL  ((size_t)96924992)   // 1024
#define OFF_XTH0 ((size_t)96926016)
#define OFF_XTH1 ((size_t)100202816)
#define OFF_XTH2 ((size_t)106756416)
#define OFF_XTL0 ((size_t)119863616)
#define OFF_XTL1 ((size_t)123140416)
#define OFF_XTL2 ((size_t)129694016)
#define NEED_FULL ((size_t)142801216)
#define ZERO_U32  ((u32)166352)            // (262144+64+403200)/4, hist..logits
#define Y01_LEN   ((size_t)(6553600 + 13107200))   // y0 + y1 for K-split atomics

// ---------------- bf16 helpers (RNE, finite inputs) ----------------
__device__ __forceinline__ short f2bf(float f) {
    u32 u = __float_as_uint(f);
    u = (u + 0x7fffu + ((u >> 16) & 1u)) >> 16;
    return (short)u;
}
__device__ __forceinline__ float bf2f(short h) {
    return __uint_as_float(((u32)(unsigned short)h) << 16);
}

// ---- weight prep (merged 3 heads + workspace zeroing) ----
// Fragment-ordered layout: [my(co/128)][ch(ci/32)][tap(9)][m(128)][ci(32)]
// Blocks [0,163): zero hist+meta+logits. Then 4096 head0, 1024 head1, 256 head2.
__global__ __launch_bounds__(256) void prep_w_all(
    const float* __restrict__ w0, short* __restrict__ wh0, short* __restrict__ wl0,
    const float* __restrict__ w1, short* __restrict__ wh1, short* __restrict__ wl1,
    const float* __restrict__ w2, short* __restrict__ wh2, short* __restrict__ wl2,
    u32* __restrict__ zbase)
{
    u32 b = blockIdx.x;
    if (b < 163) {
        u32 i = (b * 256 + threadIdx.x) * 4;
        if (i + 4 <= ZERO_U32) {
            *(uint4*)(zbase + i) = make_uint4(0u, 0u, 0u, 0u);
        } else {
            for (u32 k = i; k < ZERO_U32; ++k) zbase[k] = 0u;
        }
        return;
    }
    b -= 163;
    const float* w; short* wh; short* wl; int C;
    if (b < 4096)      { w = w0; wh = wh0; wl = wl0; C = 1024; }
    else if (b < 5120) { b -= 4096; w = w1; wh = wh1; wl = wl1; C = 512; }
    else               { b -= 5120; w = w2; wh = wh2; wl = wl2; C = 256; }

    __shared__ float ws_[2304];
    int chunks256 = C >> 8;
    int co = (int)b / chunks256;
    int ci0 = ((int)b % chunks256) << 8;
    size_t base = ((size_t)co * C + ci0) * 9;
    for (int idx = threadIdx.x; idx < 2304; idx += 256) ws_[idx] = w[base + idx];
    __syncthreads();
    int my = co >> 7, m = co & 127;
    int chunksW = C >> 5;
    for (int idx = threadIdx.x; idx < 2304; idx += 256) {
        int tap = idx >> 8, ci = idx & 255;
        float v = ws_[ci * 9 + tap];
        short h = f2bf(v);
        short l = f2bf(v - bf2f(h));
        int gci = ci0 + ci;
        int ch = gci >> 5, ciw = gci & 31;
        size_t o = ((((size_t)my * chunksW + ch) * 9 + tap) * 128 + m) * 32 + ciw;
        wh[o] = h; wl[o] = l;
    }
}

// ---------------- input prep: [C][HW] f32 -> [pix][C] bf16 hi/lo (transpose) --
// Blocks >= 11200 zero y0+y1 (needed by conv's K-split atomics).
struct PrepX { const float* x; short* xh; short* xl; int C, HW, bbase, ptiles; };

__global__ __launch_bounds__(256) void prep_x_kernel(PrepX p0, PrepX p1, PrepX p2,
                                                     float* __restrict__ y01)
{
    if (blockIdx.x >= 11200u) {
        u32 zb = blockIdx.x - 11200u;
        uint4* z = (uint4*)y01;
        u32 i = (zb * 256 + threadIdx.x) * 2;
        z[i]     = make_uint4(0u, 0u, 0u, 0u);
        z[i + 1] = make_uint4(0u, 0u, 0u, 0u);
        return;
    }
    PrepX p = (blockIdx.x >= (u32)p2.bbase) ? p2 :
              (blockIdx.x >= (u32)p1.bbase) ? p1 : p0;
    int local = blockIdx.x - p.bbase;
    int pt = local % p.ptiles, ct = local / p.ptiles;
    __shared__ short th[32][34];
    __shared__ short tl[32][34];
    for (int idx = threadIdx.x; idx < 1024; idx += 256) {
        int ci = idx >> 5, px = idx & 31;
        float v = p.x[(size_t)(ct * 32 + ci) * p.HW + pt * 32 + px];
        short h = f2bf(v);
        th[ci][px] = h;
        tl[ci][px] = f2bf(v - bf2f(h));
    }
    __syncthreads();
    for (int idx = threadIdx.x; idx < 1024; idx += 256) {
        int px = idx >> 5, ci = idx & 31;
        size_t o = (size_t)(pt * 32 + px) * p.C + ct * 32 + ci;
        p.xh[o] = th[ci][px];
        p.xl[o] = tl[ci][px];
    }
}

// ------- fused 3-head 3x3 conv, bf16 MFMA hi/lo 3-pass, tap-reuse hood -------
// R11: R8 barrier-free tap loop + 3-DEEP register prefetch (2 taps ahead) for
// BOTH A-hi and A-lo. Per-XCD A working set (4.7MB head0) exceeds 4MB L2 ->
// ~half the A-loads are L3 hits (~600cy); R8's 1-tap-ahead (~233cy of MFMA)
// left ~400cy exposed per tap (matches the 35% MfmaUtil plateau across
// R4-R10). Issue-to-use distance is now ~466cy of MFMAs. Ring slots are
// mod-3 with static indices (full unroll) -> stays in registers.
// K-split retained: every block does exactly 8 chunks; head0 4-way, head1
// 2-way over the reduction (partial y via atomicAdd, y pre-zeroed).
struct ConvHead {
    const float* x; const short* xh; const short* xl;
    const short* wh; const short* wl; const float* bias;
    const float* w1; float* y;
    int C, H, W, sx, nco_mask, nco_shift, kmask, kshift, chunks, bbase, lbase;
};

__global__ __launch_bounds__(256, 2) void conv3x3_mfma(
    ConvHead h0, ConvHead h1, ConvHead h2, float* __restrict__ logits, int use_xt)
{
    ConvHead h = (blockIdx.x >= (u32)h2.bbase) ? h2 :
                 (blockIdx.x >= (u32)h1.bbase) ? h1 : h0;
    const int local = blockIdx.x - h.bbase;
    const int my = local & h.nco_mask;
    const int rest = local >> h.nco_shift;
    const int kb = rest & h.kmask;
    const int sp = rest >> h.kshift;
    const int ty = sp / h.sx;
    const int tx = sp - ty * h.sx;
    const int py0 = ty * 8, px0 = tx * 16;
    const int co0 = my * 128;
    const int C = h.C, H = h.H, W = h.W, HW = H * W;

    const int tid = threadIdx.x;
    const int lane = tid & 63;
    const int wave = tid >> 6;
    const int quad = lane >> 4;
    const int l15 = lane & 15;
    const int wm = wave >> 1, wn = wave & 1;

    __shared__ short Bh_hi[180 * BPAD];   // 10 x 18 pixel hood x 32 ch
    __shared__ short Bh_lo[180 * BPAD];
    __shared__ float wobj[3][128];

    f32x4 acc[4][4];
    #pragma unroll
    for (int i = 0; i < 4; i++)
        #pragma unroll
        for (int j = 0; j < 4; j++) acc[i][j] = (f32x4){0.f, 0.f, 0.f, 0.f};

    const int chunksW = C >> 5;
    const size_t mybase = (size_t)my * chunksW * 9 * 4096;
    const int lane_off = wm * 2048 + l15 * 32 + quad * 8;
    const short* __restrict__ wh_lane = h.wh + mybase + lane_off;
    const short* __restrict__ wl_lane = h.wl + mybase + lane_off;
    const int ch0 = kb * h.chunks;
    const int glim = h.chunks * 9;      // local global-tap count

    // 3-deep prefetch rings, slot = (local global tap) % 3
    short8 pah[3][4], pal[3][4];

    // prologue: stage local taps 0 and 1
    {
        const size_t g0 = (size_t)(ch0 * 9) * 4096;
        #pragma unroll
        for (int mt = 0; mt < 4; mt++) {
            pah[0][mt] = *(const short8*)(wh_lane + g0 + mt * 512);
            pal[0][mt] = *(const short8*)(wl_lane + g0 + mt * 512);
            pah[1][mt] = *(const short8*)(wh_lane + g0 + 4096 + mt * 512);
            pal[1][mt] = *(const short8*)(wl_lane + g0 + 4096 + mt * 512);
        }
    }

    for (int c = 0; c < h.chunks; ++c) {
        const int ch = ch0 + c;
        const int ci0 = ch << 5;
        __syncthreads();   // prev chunk B reads fully consumed
        // ---- stage hood: 180 pixels x 32 channels, hi/lo, zero-padded ----
        for (int idx = tid; idx < 360; idx += 256) {
            int hp = idx >> 1, half = idx & 1;
            int hy = hp / 18, hx = hp - hy * 18;
            int gy = py0 - 1 + hy, gx = px0 - 1 + hx;
            short8 vh0 = {0,0,0,0,0,0,0,0}, vh1 = {0,0,0,0,0,0,0,0};
            short8 vl0 = {0,0,0,0,0,0,0,0}, vl1 = {0,0,0,0,0,0,0,0};
            if (gy >= 0 && gy < H && gx >= 0 && gx < W) {
                if (use_xt) {
                    size_t ro = (size_t)(gy * W + gx) * C + ci0 + half * 16;
                    const short* ph = h.xh + ro;
                    const short* pl = h.xl + ro;
                    vh0 = *(const short8*)ph; vh1 = *(const short8*)(ph + 8);
                    vl0 = *(const short8*)pl; vl1 = *(const short8*)(pl + 8);
                } else {
                    const float* xp = h.x + (size_t)(ci0 + half * 16) * HW + gy * W + gx;
                    #pragma unroll
                    for (int k = 0; k < 8; k++) {
                        float v = xp[(size_t)k * HW];
                        short hh = f2bf(v); vh0[k] = hh; vl0[k] = f2bf(v - bf2f(hh));
                    }
                    #pragma unroll
                    for (int k = 0; k < 8; k++) {
                        float v = xp[(size_t)(k + 8) * HW];
                        short hh = f2bf(v); vh1[k] = hh; vl1[k] = f2bf(v - bf2f(hh));
                    }
                }
            }
            int bo = hp * BPAD + half * 16;
            *(short8*)&Bh_hi[bo]     = vh0;
            *(short8*)&Bh_hi[bo + 8] = vh1;
            *(short8*)&Bh_lo[bo]     = vl0;
            *(short8*)&Bh_lo[bo + 8] = vl1;
        }
        __syncthreads();   // hood visible; NO more barriers for 9 taps

        #pragma unroll
        for (int tap = 0; tap < 9; ++tap) {
            const int gl = c * 9 + tap;        // local global tap
            const int s  = tap % 3;            // slot holding this tap's A
            const int dy = tap / 3, dx = tap - dy * 3;   // 0..2
            short8 bh[4], bl[4];
            #pragma unroll
            for (int nt = 0; nt < 4; nt++) {
                int n = wn * 64 + nt * 16 + l15;
                int ro = ((((n >> 4) + dy) * 18) + (n & 15) + dx) * BPAD + quad * 8;
                bh[nt] = *(const short8*)&Bh_hi[ro];
                bl[nt] = *(const short8*)&Bh_lo[ro];
            }
            // stage A for tap gl+2 into slot (tap+2)%3 — 2 taps (~466cy) ahead
            if (gl + 2 < glim) {
                const int s2 = (tap + 2) % 3;
                const size_t goff = (size_t)(ch0 * 9 + gl + 2) * 4096;
                #pragma unroll
                for (int mt = 0; mt < 4; mt++) {
                    pah[s2][mt] = *(const short8*)(wh_lane + goff + mt * 512);
                    pal[s2][mt] = *(const short8*)(wl_lane + goff + mt * 512);
                }
            }
            __builtin_amdgcn_s_setprio(1);
            // pass 1: hi x hi -- 16 independent MFMAs
            #pragma unroll
            for (int mt = 0; mt < 4; mt++)
                #pragma unroll
                for (int nt = 0; nt < 4; nt++)
                    acc[mt][nt] = __builtin_amdgcn_mfma_f32_16x16x32_bf16(pah[s][mt], bh[nt], acc[mt][nt], 0, 0, 0);
            // pass 2: lo x hi
            #pragma unroll
            for (int mt = 0; mt < 4; mt++)
                #pragma unroll
                for (int nt = 0; nt < 4; nt++)
                    acc[mt][nt] = __builtin_amdgcn_mfma_f32_16x16x32_bf16(pal[s][mt], bh[nt], acc[mt][nt], 0, 0, 0);
            // pass 3: hi x lo
            #pragma unroll
            for (int mt = 0; mt < 4; mt++)
                #pragma unroll
                for (int nt = 0; nt < 4; nt++)
                    acc[mt][nt] = __builtin_amdgcn_mfma_f32_16x16x32_bf16(pah[s][mt], bl[nt], acc[mt][nt], 0, 0, 0);
            __builtin_amdgcn_s_setprio(0);
        }
    }

    // ---- epilogue: y += acc (+bias on kb==0); fused objectness partial dot --
    for (int idx = tid; idx < 384; idx += 256) {
        int a = idx >> 7, m = idx & 127;
        wobj[a][m] = h.w1[(size_t)(a * 85 + 4) * C + co0 + m];
    }
    __syncthreads();
    const bool ksplit = (h.kmask != 0);
    #pragma unroll
    for (int nt = 0; nt < 4; nt++) {
        int n = wn * 64 + nt * 16 + l15;
        int py = py0 + (n >> 4), px = px0 + (n & 15);
        if (px < W) {
            int p = py * W + px;
            float s0 = 0.f, s1 = 0.f, s2 = 0.f;
            #pragma unroll
            for (int mt = 0; mt < 4; mt++) {
                #pragma unroll
                for (int r = 0; r < 4; r++) {
                    int m = wm * 64 + mt * 16 + quad * 4 + r;
                    int co = co0 + m;
                    float yv = acc[mt][nt][r] + (kb == 0 ? h.bias[co] : 0.f);
                    if (ksplit) atomicAdd(&h.y[(size_t)co * HW + p], yv);
                    else        h.y[(size_t)co * HW + p] = yv;
                    s0 = fmaf(yv, wobj[0][m], s0);
                    s1 = fmaf(yv, wobj[1][m], s1);
                    s2 = fmaf(yv, wobj[2][m], s2);
                }
            }
            atomicAdd(&logits[h.lbase + p], s0);
            atomicAdd(&logits[h.lbase + HW + p], s1);
            atomicAdd(&logits[h.lbase + 2 * HW + p], s2);
        }
    }
}

// ---------------- keys: logits -> sigmoid -> sort key + histogram ------------
__global__ __launch_bounds__(256) void keys_kernel(
    const float* __restrict__ logits,
    const float* __restrict__ b10, const float* __restrict__ b11, const float* __restrict__ b12,
    u64* __restrict__ keys, u32* __restrict__ hist)
{
    int i = blockIdx.x * 256 + threadIdx.x;
    if (i >= NBOX) return;
    float bias;
    if (i < 4800)       bias = b10[(i / 1600) * 85 + 4];
    else if (i < 24000) bias = b11[((i - 4800) / 6400) * 85 + 4];
    else                bias = b12[((i - 24000) / 25600) * 85 + 4];
    float s = 1.0f / (1.0f + expf(-(logits[i] + bias)));
    u64 k = ((u64)__float_as_uint(s) << 32) | (u64)(0xFFFFFFFFu - (u32)i);
    keys[i] = k;
    atomicAdd(&hist[(u32)(k >> 48)], 1u);
}

// ---------------- top-256 selection ----------------
__global__ __launch_bounds__(256) void select_kernel(const u32* __restrict__ hist,
                                                     u32* __restrict__ meta)
{
    __shared__ u32 csum[256];
    int t = threadIdx.x;
    const uint4* h4 = (const uint4*)(hist + t * 256);
    u32 s = 0;
    #pragma unroll 8
    for (int i = 0; i < 64; i++) { uint4 v = h4[i]; s += v.x + v.y + v.z + v.w; }
    csum[t] = s;
    __syncthreads();
    if (t == 0) {
        u32 cum = 0; int chunk = 255;
        for (; chunk > 0; chunk--) {
            if (cum + csum[chunk] >= 256u) break;
            cum += csum[chunk];
        }
        int B = chunk * 256;
        u32 cumAbove = cum;
        for (int bb = chunk * 256 + 255; bb >= chunk * 256; bb--) {
            u32 h = hist[bb];
            if (cumAbove + h >= 256u) { B = bb; break; }
            cumAbove += h;
        }
        meta[0] = (u32)B;
        meta[1] = cumAbove;
    }
}

__global__ __launch_bounds__(256) void compact_kernel(
    const u64* __restrict__ keys, int n, const u32* __restrict__ meta,
    u64* __restrict__ cand, u32* __restrict__ count)
{
    int i = blockIdx.x * blockDim.x + threadIdx.x;
    if (i < n) {
        u64 k = keys[i];
        if ((u32)(k >> 48) >= meta[0]) {
            u32 pos = atomicAdd(count, 1u);
            if (pos < CAND_CAP) cand[pos] = k;
        }
    }
}

// Dynamic bitonic size — sort next_pow2(n) >= 256 instead of always 4096.
__global__ __launch_bounds__(1024) void sort_select_kernel(
    const u64* __restrict__ cand, const u32* __restrict__ meta,
    u32* __restrict__ sel)
{
    __shared__ u64 sk[CAND_CAP];
    int n = (int)meta[2];
    if (n > CAND_CAP) n = CAND_CAP;
    int P = 256;
    while (P < n) P <<= 1;          // 256 <= P <= 4096, uniform across block
    for (int i = threadIdx.x; i < P; i += 1024)
        sk[i] = (i < n) ? cand[i] : 0ull;
    __syncthreads();
    for (int k = 2; k <= P; k <<= 1) {
        for (int j = k >> 1; j > 0; j >>= 1) {
            for (int i = threadIdx.x; i < P; i += 1024) {
                int ixj = i ^ j;
                if (ixj > i) {
                    u64 a = sk[i], c = sk[ixj];
                    bool sw = ((i & k) == 0) ? (a > c) : (a < c);
                    if (sw) { sk[i] = c; sk[ixj] = a; }
                }
            }
            __syncthreads();
        }
    }
    if (threadIdx.x < 256) {
        u64 k = sk[P - 1 - threadIdx.x];
        sel[threadIdx.x] = 0xFFFFFFFFu - (u32)(k & 0xFFFFFFFFull);
    }
}

// ---------------- final: full 85-ch 1x1 conv + decode for the 256 winners ---
__global__ __launch_bounds__(256) void final_kernel(
    const float* __restrict__ y0, const float* __restrict__ y1, const float* __restrict__ y2,
    const float* __restrict__ w10, const float* __restrict__ w11, const float* __restrict__ w12,
    const float* __restrict__ b10, const float* __restrict__ b11, const float* __restrict__ b12,
    const u32* __restrict__ sel, float* __restrict__ out)
{
    int b = blockIdx.x;
    u32 bi = sel[b];
    const float *y, *w1, *b1;
    int C, H, W, base; float ratio;
    float anchs[6];
    if (bi < 4800u) {
        y = y0; w1 = w10; b1 = b10; C = 1024; H = 40; W = 40; base = 0; ratio = 32.f;
        anchs[0]=116.f; anchs[1]=90.f; anchs[2]=156.f; anchs[3]=198.f; anchs[4]=373.f; anchs[5]=326.f;
    } else if (bi < 24000u) {
        y = y1; w1 = w11; b1 = b11; C = 512; H = 80; W = 80; base = 4800; ratio = 16.f;
        anchs[0]=30.f; anchs[1]=61.f; anchs[2]=62.f; anchs[3]=45.f; anchs[4]=59.f; anchs[5]=119.f;
    } else {
        y = y2; w1 = w12; b1 = b12; C = 256; H = 160; W = 160; base = 24000; ratio = 8.f;
        anchs[0]=10.f; anchs[1]=13.f; anchs[2]=16.f; anchs[3]=30.f; anchs[4]=33.f; anchs[5]=23.f;
    }
    int HW = H * W;
    int r = (int)bi - base;
    int a = r / HW, p = r % HW;
    __shared__ float ys[256];
    int c = threadIdx.x;
    float acc = 0.f;
    const float* wrow = w1 + (size_t)(a * 85 + (c < 85 ? c : 0)) * C;
    for (int ci0 = 0; ci0 < C; ci0 += 256) {
        __syncthreads();
        ys[c] = y[(size_t)(ci0 + c) * HW + p];
        __syncthreads();
        if (c < 85)
            for (int ci = 0; ci < 256; ci++) acc = fmaf(ys[ci], wrow[ci0 + ci], acc);
    }
    if (c < 85) {
        float v = acc + b1[a * 85 + c];
        float s = 1.0f / (1.0f + expf(-v));
        int py = p / W, px = p - (p / W) * W;
        float o;
        if (c == 0)      o = (s * 2.0f - 0.5f + (float)px) * ratio;
        else if (c == 1) o = (s * 2.0f - 0.5f + (float)py) * ratio;
        else if (c == 2) { float t = s * 2.0f; o = t * t * anchs[a * 2]; }
        else if (c == 3) { float t = s * 2.0f; o = t * t * anchs[a * 2 + 1]; }
        else             o = s;
        out[(size_t)b * 85 + c] = o;
    }
}

// ---------------- launch ----------------
extern "C" void kernel_launch(void* const* d_in, const int* in_sizes, int n_in,
                              void* d_out, int out_size, void* d_ws, size_t ws_size,
                              hipStream_t stream)
{
    const float* feat0 = (const float*)d_in[0];   // (256,160,160)
    const float* feat1 = (const float*)d_in[1];   // (512,80,80)
    const float* feat2 = (const float*)d_in[2];   // (1024,40,40)
    const float* w3_0 = (const float*)d_in[3];  const float* b3_0 = (const float*)d_in[4];
    const float* w1_0 = (const float*)d_in[5];  const float* b1_0 = (const float*)d_in[6];
    const float* w3_1 = (const float*)d_in[7];  const float* b3_1 = (const float*)d_in[8];
    const float* w1_1 = (const float*)d_in[9];  const float* b1_1 = (const float*)d_in[10];
    const float* w3_2 = (const float*)d_in[11]; const float* b3_2 = (const float*)d_in[12];
    const float* w1_2 = (const float*)d_in[13]; const float* b1_2 = (const float*)d_in[14];

    char* ws = (char*)d_ws;
    short* wth0 = (short*)(ws + OFF_WTH0);
    short* wth1 = (short*)(ws + OFF_WTH1);
    short* wth2 = (short*)(ws + OFF_WTH2);
    short* wtl0 = (short*)(ws + OFF_WTL0);
    short* wtl1 = (short*)(ws + OFF_WTL1);
    short* wtl2 = (short*)(ws + OFF_WTL2);
    float* y0   = (float*)(ws + OFF_Y0);
    float* y1   = (float*)(ws + OFF_Y1);
    float* y2   = (float*)(ws + OFF_Y2);
    u64*   keys = (u64*)  (ws + OFF_KEYS);
    u32*   hist = (u32*)  (ws + OFF_HIST);
    u32*   meta = (u32*)  (ws + OFF_META);
    float* logits = (float*)(ws + OFF_LOG);
    u64*   cand = (u64*)  (ws + OFF_CAND);
    u32*   sel  = (u32*)  (ws + OFF_SEL);

    const int use_xt = (ws_size >= NEED_FULL) ? 1 : 0;
    short* xth0 = (short*)(ws + OFF_XTH0);
    short* xth1 = (short*)(ws + OFF_XTH1);
    short* xth2 = (short*)(ws + OFF_XTH2);
    short* xtl0 = (short*)(ws + OFF_XTL0);
    short* xtl1 = (short*)(ws + OFF_XTL1);
    short* xtl2 = (short*)(ws + OFF_XTL2);

    // weight transforms (fragment-ordered) + hist/meta/logits zeroing, 1 launch
    prep_w_all<<<163 + 4096 + 1024 + 256, 256, 0, stream>>>(
        w3_0, wth0, wtl0, w3_1, wth1, wtl1, w3_2, wth2, wtl2, (u32*)(ws + OFF_HIST));

    // input transpose + bf16 split; extra 2400 blocks zero y0+y1
    if (use_xt) {
        PrepX p0 = {feat2, xth0, xtl0, 1024, 1600,  0,    50};
        PrepX p1 = {feat1, xth1, xtl1, 512,  6400,  1600, 200};
        PrepX p2 = {feat0, xth2, xtl2, 256,  25600, 4800, 800};
        prep_x_kernel<<<13600, 256, 0, stream>>>(p0, p1, p2, y0);
    } else {
        hipMemsetAsync(ws + OFF_Y0, 0, Y01_LEN, stream);
    }

    // fused 3-head 3x3 conv (+ objectness partials), K-split for balance:
    // head0: 8 co x 4 kb x 15 sp = 480; head1: 4 x 2 x 50 = 400; head2: 2 x 1 x 200 = 400
    ConvHead h0 = {feat2, xth0, xtl0, wth0, wtl0, b3_0, w1_0, y0, 1024, 40,  40,  3,  7, 3, 3, 2, 8, 0,   0};
    ConvHead h1 = {feat1, xth1, xtl1, wth1, wtl1, b3_1, w1_1, y1, 512,  80,  80,  5,  3, 2, 1, 1, 8, 480, 4800};
    ConvHead h2 = {feat0, xth2, xtl2, wth2, wtl2, b3_2, w1_2, y2, 256,  160, 160, 10, 1, 1, 0, 0, 8, 880, 24000};
    conv3x3_mfma<<<1280, 256, 0, stream>>>(h0, h1, h2, logits, use_xt);

    // keys + histogram from logits
    keys_kernel<<<(NBOX + 255) / 256, 256, 0, stream>>>(logits, b1_0, b1_1, b1_2, keys, hist);

    // top-256
    select_kernel<<<1, 256, 0, stream>>>(hist, meta);
    compact_kernel<<<(NBOX + 255) / 256, 256, 0, stream>>>(keys, NBOX, meta, cand, meta + 2);
    sort_select_kernel<<<1, 1024, 0, stream>>>(cand, meta, sel);

    // full 85-channel compute + decode for winners only
    final_kernel<<<256, 256, 0, stream>>>(y0, y1, y2, w1_0, w1_1, w1_2,
                                          b1_0, b1_1, b1_2, sel, (float*)d_out);
}